// Round 2
// baseline (393.221 us; speedup 1.0000x reference)
//
#include <hip/hip_runtime.h>

#define NUM_DENSE 13
#define NUM_SPARSE 26
#define FEAT_NUM 40000
#define FEATURE_LENGTH (NUM_SPARSE * FEAT_NUM + NUM_DENSE)  // 1,040,013
#define KDIM 64
#define BATCH 4096
#define QSIZE 4000          // floats per LDS chunk: 10 chunks per 40000-window
#define NCHUNK 10
#define LDSN (QSIZE + 4)    // 4004 floats = 16,016 B (exact max write incl. align shift)
#define NT 1024
#define NG 8                // j-groups -> 512 blocks = 2 blocks/CU
#define NBUF 4              // 4-deep LDS ring, 2-stage lookahead

// Kernel 0: transpose sparse indices to [slot][batch] (raw 0..39999 values).
__global__ void transpose_kernel(const int* __restrict__ sp, int* __restrict__ sp_t) {
    int tid = blockIdx.x * blockDim.x + threadIdx.x;  // tid = j*BATCH + b
    int j = tid >> 12;
    int b = tid & 4095;
    sp_t[tid] = sp[b * NUM_SPARSE + j];
}

// async global->LDS, 16B per lane; HW dest = wave-uniform(base) + lane*16.
// We pass per-lane pointers where lane L's value == base + L*16, matching HW.
__device__ __forceinline__ void load_lds16(const float4* g, float* l) {
    __builtin_amdgcn_global_load_lds(
        (const __attribute__((address_space(1))) void*)g,
        (__attribute__((address_space(3))) void*)l, 16, 0, 0);
}

// Kernel 1: 4-buffer ring, counted-vmcnt pipeline (T3/T4 pattern).
// Exactly ONE global_load_lds per wave per stage -> vmcnt ticks are exact.
// Loop: issue(s+2) -> s_waitcnt vmcnt(2) -> s_barrier -> gather buf[s&3].
// Stages s+1/s+2 stay in flight ACROSS the barrier (never drain to 0), so the
// per-stage period is transfer-bound, not latency/drain-bound.
// Race audit (depth 4, lookahead 2): writer of buf[(s+2)&3] at iter s has
// passed barrier(s-1); all waves pass barrier(s-1) only after finishing
// gather(s-2), the last reader of that buffer. WAR/WAW/RAW all covered.
// Safety: any compiler-emitted vmem op (spill etc.) is a NEWER queue entry,
// making the counted wait more conservative -- never a race.
__global__ __launch_bounds__(NT, 8) void accum_kernel(const float* __restrict__ V,
                                                      const int* __restrict__ sp_t,
                                                      float* __restrict__ PS,
                                                      float* __restrict__ PQ) {
    __shared__ __align__(16) float buf[NBUF][LDSN];   // 4 x 16,016 B = 64 KB

    const int k = blockIdx.x;
    const int g = blockIdx.y;
    const int tid = threadIdx.x;
    const int jstart = (g * NUM_SPARSE) / NG;        // 0,3,6,9,13,16,19,22
    const int jend   = ((g + 1) * NUM_SPARSE) / NG;  // 3,6,9,13,16,19,22,26
    const int nw     = jend - jstart;                // 3 or 4 windows

    const size_t kbase = (size_t)k * FEATURE_LENGTH + NUM_DENSE;
    const int a   = (int)(kbase & 3);        // = (k+1)&3; k=63 -> 0 (exact end, no OOB)
    const int nl4 = (QSIZE + a + 3) >> 2;    // 1000 or 1001 float4 loads per chunk
    const int nstage = nw * NCHUNK;

    // ---- preload ALL window indices into named registers BEFORE the loop
    //      (no vmem in main loop -> vmcnt bookkeeping stays exact; no
    //      runtime-indexed arrays -> no scratch) ----
    int s0[4], s1[4], s2[4], s3[4];
#pragma unroll
    for (int r = 0; r < 4; ++r) {
        s0[r] = sp_t[(jstart + 0) * BATCH + tid + NT * r];
        s1[r] = sp_t[(jstart + 1) * BATCH + tid + NT * r];
        s2[r] = sp_t[(jstart + 2) * BATCH + tid + NT * r];
    }
    if (nw == 4) {
#pragma unroll
        for (int r = 0; r < 4; ++r) s3[r] = sp_t[(jstart + 3) * BATCH + tid + NT * r];
    } else {
#pragma unroll
        for (int r = 0; r < 4; ++r) s3[r] = 0;
    }

    float sAcc[4] = {0.f, 0.f, 0.f, 0.f};
    float qAcc[4] = {0.f, 0.f, 0.f, 0.f};
    int cs[4];
#pragma unroll
    for (int r = 0; r < 4; ++r) cs[r] = s0[r];

    // drain index loads so the vm queue is EMPTY entering the pipeline
    __syncthreads();

    auto issue = [&](int t) {
        const int w = t / NCHUNK;
        const int q = t - w * NCHUNK;
        const float4* __restrict__ g4 =
            (const float4*)(V + (kbase + (size_t)(jstart + w) * FEAT_NUM
                                       + (size_t)q * QSIZE) - a);
        if (tid < nl4)   // nl4 >= 1000 > 960: every wave issues exactly 1 inst
            load_lds16(g4 + tid, &buf[t & 3][4 * tid]);
    };

    // prologue: stages 0 and 1 in flight
    issue(0);
    issue(1);

    int wg = 0, qg = 0;
    for (int s = 0; s < nstage; ++s) {
        const int t = s + 2;
        if (t < nstage) issue(t);

        // counted wait: stage s resident; s+1/s+2 remain in flight across barrier
        const int ahead = nstage - 1 - s;
        if (ahead >= 2)      asm volatile("s_waitcnt vmcnt(2)" ::: "memory");
        else if (ahead == 1) asm volatile("s_waitcnt vmcnt(1)" ::: "memory");
        else                 asm volatile("s_waitcnt vmcnt(0)" ::: "memory");
        __builtin_amdgcn_s_barrier();
        asm volatile("" ::: "memory");   // keep gather reads below the barrier

        const int q0 = qg * QSIZE;
        const float* __restrict__ bb = buf[s & 3];
#pragma unroll
        for (int r = 0; r < 4; ++r) {
            int rel = cs[r] - q0;
            bool in = (rel >= 0) && (rel < QSIZE);
            int addr = in ? (rel + a) : 0;   // masked lanes: broadcast read, free
            float v = bb[addr];
            v = in ? v : 0.f;
            sAcc[r] += v;
            qAcc[r] += v * v;
        }

        // advance gather pointer; window rollover re-selects cached indices
        if (++qg == NCHUNK) {
            qg = 0; ++wg;
            if (wg < nw) {
#pragma unroll
                for (int r = 0; r < 4; ++r)
                    cs[r] = (wg == 1) ? s1[r] : (wg == 2) ? s2[r] : s3[r];
            }
        }
    }

    const int base = (g * KDIM + k) * BATCH + tid;   // [g][k][b]
#pragma unroll
    for (int r = 0; r < 4; ++r) {
        PS[base + NT * r] = sAcc[r];
        PQ[base + NT * r] = qAcc[r];
    }
}

// Kernel 2: 256 blocks x 256 threads. Block = 16 batch rows; thread (bi, ki)
// covers b = blk*16+bi and 4 k values; LDS-reduce over ki; 16 threads finish
// first-order terms + output. Wave reads of PS/PQ: 64 lanes = 16 consecutive
// b x 4 k-rows = 4 fully-consumed 64B lines per instruction (coalesced).
__global__ __launch_bounds__(256) void final_kernel(const float* __restrict__ dense,
                                                    const float* __restrict__ w0,
                                                    const float* __restrict__ w,
                                                    const float* __restrict__ V,
                                                    const int* __restrict__ sp_t,
                                                    const float* __restrict__ PS,
                                                    const float* __restrict__ PQ,
                                                    float* __restrict__ out) {
    __shared__ float red[16][17];
    const int tid = threadIdx.x;
    const int bi  = tid & 15;
    const int ki  = tid >> 4;                 // 0..15
    const int b   = blockIdx.x * 16 + bi;

    float x[NUM_DENSE], x2[NUM_DENSE];
#pragma unroll
    for (int d = 0; d < NUM_DENSE; ++d) {
        x[d]  = dense[b * NUM_DENSE + d];     // L1-hot (16 b per block)
        x2[d] = x[d] * x[d];
    }

    float t = 0.f;
#pragma unroll
    for (int kk = 0; kk < 4; ++kk) {
        const int k = ki * 4 + kk;
        float sv = 0.f, qv = 0.f;
#pragma unroll
        for (int g = 0; g < NG; ++g) {
            sv += PS[((g << 6) + k) * BATCH + b];
            qv += PQ[((g << 6) + k) * BATCH + b];
        }
        const float* __restrict__ Vk = V + (size_t)k * FEATURE_LENGTH;
#pragma unroll
        for (int d = 0; d < NUM_DENSE; ++d) {
            float vv = Vk[d];                 // 64x13 distinct values, L2-hot
            sv += x[d] * vv;
            qv += x2[d] * vv * vv;
        }
        t += sv * sv - qv;
    }
    red[bi][ki] = 0.5f * t;
    __syncthreads();

    if (tid < 16) {                           // tid == bi, one thread per row
        const int bb = blockIdx.x * 16 + tid;
        float acc = w0[0];
#pragma unroll
        for (int i = 0; i < 16; ++i) acc += red[tid][i];
        // first-order sparse (w gather, 4MB table, L3-hot)
#pragma unroll
        for (int j = 0; j < NUM_SPARSE; ++j)
            acc += w[NUM_DENSE + j * FEAT_NUM + sp_t[j * BATCH + bb]];
        // first-order dense
#pragma unroll
        for (int d = 0; d < NUM_DENSE; ++d) acc += x[d] * w[d];
        out[bb] = acc;
    }
}

extern "C" void kernel_launch(void* const* d_in, const int* in_sizes, int n_in,
                              void* d_out, int out_size, void* d_ws, size_t ws_size,
                              hipStream_t stream) {
    const float* dense  = (const float*)d_in[0];
    const int*   sparse = (const int*)d_in[1];
    const float* w0     = (const float*)d_in[2];
    const float* w      = (const float*)d_in[3];
    const float* V      = (const float*)d_in[4];
    float* out = (float*)d_out;

    char* ws = (char*)d_ws;
    int*   sp_t = (int*)ws;                               // 26*4096*4 = 425,984 B
    float* PS   = (float*)(ws + (1 << 20));               // 8*64*4096*4 = 8.39 MB
    float* PQ   = (float*)(ws + (1 << 20) + NG * KDIM * BATCH * 4);

    transpose_kernel<<<(NUM_SPARSE * BATCH) / 256, 256, 0, stream>>>(sparse, sp_t);
    accum_kernel<<<dim3(KDIM, NG), NT, 0, stream>>>(V, sp_t, PS, PQ);
    final_kernel<<<BATCH / 16, 256, 0, stream>>>(dense, w0, w, V, sp_t, PS, PQ, out);
}